// Round 2
// baseline (1023.845 us; speedup 1.0000x reference)
//
#include <hip/hip_runtime.h>

#define E_EDGES 262144
#define N_NODES 32768
#define HDIM 256

typedef __bf16 bf16;
typedef __attribute__((ext_vector_type(8))) __bf16 bf16x8;
typedef __attribute__((ext_vector_type(4))) __bf16 bf16x4;
typedef __attribute__((ext_vector_type(4))) float f32x4;
typedef __attribute__((ext_vector_type(4))) int i32x4;

__device__ __forceinline__ float sigm(float z) { return 1.0f / (1.0f + __expf(-z)); }
__device__ __forceinline__ float tanh_(float z) { return 1.0f - 2.0f / (1.0f + __expf(2.0f * z)); }

// ---- stage 64x256 f32 tile -> XOR-swizzled bf16 LDS [64][512B] (32 KiB) ----
// swizzle: byte ^= (row&7)<<4 (spreads stride-512B column reads across banks)
__device__ __forceinline__ void stage_tile(const float* __restrict__ src, char* lds) {
  const int t = threadIdx.x;
  const int rsub = t >> 4, l16 = t & 15;
#pragma unroll
  for (int it = 0; it < 4; ++it) {
    const int row = it * 16 + rsub;
    const float4* p = (const float4*)(src + (size_t)row * HDIM);
#pragma unroll
    for (int j = 0; j < 4; ++j) {
      float4 v = p[j * 16 + l16];  // 16 lanes read 256B contiguous per row
      unsigned byte = (unsigned)(row * 512 + (j * 16 + l16) * 8);
      byte ^= (unsigned)((row & 7) << 4);
      bf16x4 w;
      w.x = (bf16)v.x; w.y = (bf16)v.y; w.z = (bf16)v.z; w.w = (bf16)v.w;
      *(bf16x4*)(lds + byte) = w;
    }
  }
}

// ---- stage 256 W-rows x 32 k of bf16 weight (row-major [256][256]) into LDS,
// padded row stride 80B ----
__device__ __forceinline__ void stage_chunk(const bf16* __restrict__ w, int kc, char* lds) {
  const int t = threadIdx.x;  // one 64B row-chunk per thread
  const i32x4* src = (const i32x4*)(w + (size_t)t * HDIM + kc * 32);
  i32x4* dst = (i32x4*)(lds + t * 80);
#pragma unroll
  for (int j = 0; j < 4; ++j) dst[j] = src[j];
}

// ---- one K=32 chunk of MFMA; wave w owns 64 rows x cols [w*64, w*64+64).
// 8 ds_read_b128 feed 16 MFMAs (4 A-frags x 4 B-frags). ----
__device__ __forceinline__ void mfma_kc(const char* ldsA, const char* ldsB, int kc,
                                        f32x4 (&acc)[4][4]) {
  const int l = threadIdx.x & 63, w = threadIdx.x >> 6;
  const int c16 = l & 15, rg = l >> 4;
  bf16x8 a[4], b[4];
#pragma unroll
  for (int ai = 0; ai < 4; ++ai) {
    const int row = ai * 16 + c16;
    unsigned byte = (unsigned)(row * 512 + kc * 64 + (rg << 4));
    byte ^= (unsigned)((row & 7) << 4);
    a[ai] = *(const bf16x8*)(ldsA + byte);
  }
#pragma unroll
  for (int bj = 0; bj < 4; ++bj) {
    const int wrow = w * 64 + bj * 16 + c16;  // W row == output col
    b[bj] = *(const bf16x8*)(ldsB + wrow * 80 + (rg << 4));
  }
#pragma unroll
  for (int ai = 0; ai < 4; ++ai)
#pragma unroll
    for (int bj = 0; bj < 4; ++bj)
      acc[ai][bj] = __builtin_amdgcn_mfma_f32_16x16x32_bf16(a[ai], b[bj], acc[ai][bj], 0, 0, 0);
}

// ---- column segment-sum scan over the staged bf16 tile (2 cols/thread) ----
__device__ __forceinline__ void scan_cols(const char* ldsA, const int* pl,
                                          float* __restrict__ dst) {
  const int t = threadIdx.x;
  if (t < 128) {
    float a0 = 0.f, a1 = 0.f;
#pragma unroll 8
    for (int r = 0; r < 64; ++r) {
      unsigned byte = (unsigned)(r * 512 + t * 4) ^ (unsigned)((r & 7) << 4);
      unsigned v = *(const unsigned*)(ldsA + byte);
      a0 += __uint_as_float(v << 16);          // bf16 -> f32 exact
      a1 += __uint_as_float(v & 0xffff0000u);
      if (pl[r + 1] != pl[r]) {
        float* d = dst + (size_t)pl[r] * HDIM + t * 2;
        atomicAdd(d, a0);
        atomicAdd(d + 1, a1);
        a0 = 0.f; a1 = 0.f;
      }
    }
  }
}

// ---------------- kernel 0: weights f32 -> bf16 ----------------
__global__ __launch_bounds__(256) void cvt_weights(
    const float* __restrict__ uf, const float* __restrict__ wf,
    const float* __restrict__ uiou, bf16* __restrict__ ufb, bf16* __restrict__ wfb,
    bf16* __restrict__ uioub) {
  const int i = blockIdx.x * 256 + threadIdx.x;  // 65536 threads
  ufb[i] = (bf16)uf[i];
  wfb[i] = (bf16)wf[i];
#pragma unroll
  for (int j = 0; j < 3; ++j) uioub[i + j * 65536] = (bf16)uiou[i + j * 65536];
}

// ---------------- kernel 1: wfx = bf16(x @ W_f^T + b) ----------------
__global__ __launch_bounds__(256) void wfx_kernel(const float* __restrict__ x,
                                                  const bf16* __restrict__ wfb,
                                                  const float* __restrict__ wfbias,
                                                  bf16* __restrict__ wfx) {
  __shared__ char ldsA[32768];
  __shared__ char ldsB[20480];
  const int m0 = blockIdx.x * 64;
  stage_tile(x + (size_t)m0 * HDIM, ldsA);
  f32x4 acc[4][4];
#pragma unroll
  for (int ai = 0; ai < 4; ++ai)
#pragma unroll
    for (int bj = 0; bj < 4; ++bj) acc[ai][bj] = (f32x4){0.f, 0.f, 0.f, 0.f};
  for (int kc = 0; kc < 8; ++kc) {
    __syncthreads();
    stage_chunk(wfb, kc, ldsB);
    __syncthreads();
    mfma_kc(ldsA, ldsB, kc, acc);
  }
  const int l = threadIdx.x & 63, w = threadIdx.x >> 6;
  const int c16 = l & 15, rg = l >> 4;
#pragma unroll
  for (int ai = 0; ai < 4; ++ai)
#pragma unroll
    for (int bj = 0; bj < 4; ++bj) {
      const int col = w * 64 + bj * 16 + c16;
      const float bias = wfbias[col];
#pragma unroll
      for (int r = 0; r < 4; ++r) {
        const int row = m0 + ai * 16 + rg * 4 + r;
        wfx[(size_t)row * HDIM + col] = (bf16)(acc[ai][bj][r] + bias);
      }
    }
}

// ------- kernel 2: f=sigmoid(child_h@U_f^T + wfx[p]); segment sums -------
__global__ __launch_bounds__(256) void edge_kernel(
    const float* __restrict__ child_h, const float* __restrict__ child_c,
    const int* __restrict__ parent, const bf16* __restrict__ ufb,
    const bf16* __restrict__ wfx, float* __restrict__ h_sum,
    float* __restrict__ c_agg) {
  __shared__ char ldsA[32768];  // child_h bf16, later reused for f*child_c
  __shared__ char ldsB[20480];
  __shared__ int pl[65];
  // XCD-aware swizzle (4096 blocks, 8 XCDs, 512 contiguous tiles per XCD)
  const int bid = (int)blockIdx.x;
  const int blk = (bid & 7) * (E_EDGES / 64 / 8) + (bid >> 3);
  const int e0 = blk * 64;
  const int t = threadIdx.x;
  if (t < 64) pl[t] = parent[e0 + t];
  if (t == 64) pl[64] = -1;  // sentinel: always flush at r==63
  stage_tile(child_h + (size_t)e0 * HDIM, ldsA);
  __syncthreads();           // A tile + pl ready
  stage_chunk(ufb, 0, ldsB); // issue B0; latency hides under the scan
  scan_cols(ldsA, pl, h_sum);
  __syncthreads();           // B0 ready
  f32x4 acc[4][4];
#pragma unroll
  for (int ai = 0; ai < 4; ++ai)
#pragma unroll
    for (int bj = 0; bj < 4; ++bj) acc[ai][bj] = (f32x4){0.f, 0.f, 0.f, 0.f};
  mfma_kc(ldsA, ldsB, 0, acc);
  for (int kc = 1; kc < 8; ++kc) {
    __syncthreads();
    stage_chunk(ufb, kc, ldsB);
    __syncthreads();
    mfma_kc(ldsA, ldsB, kc, acc);
  }
  __syncthreads();  // all MFMA reads of ldsA done before fc overwrite
  const int l = t & 63, w = t >> 6;
  const int c16 = l & 15, rg = l >> 4;
#pragma unroll
  for (int ai = 0; ai < 4; ++ai)
#pragma unroll
    for (int bj = 0; bj < 4; ++bj) {
      const int col = w * 64 + bj * 16 + c16;
#pragma unroll
      for (int r = 0; r < 4; ++r) {
        const int row = ai * 16 + rg * 4 + r;
        const int p = pl[row];
        float z = acc[ai][bj][r] + (float)wfx[(size_t)p * HDIM + col];
        float f = sigm(z);
        float fc = f * child_c[(size_t)(e0 + row) * HDIM + col];
        unsigned byte = (unsigned)(row * 512 + col * 2) ^ (unsigned)((row & 7) << 4);
        *(bf16*)(ldsA + byte) = (bf16)fc;
      }
    }
  __syncthreads();
  scan_cols(ldsA, pl, c_agg);
}

// ------- kernel 3: iou = h_sum@U_iou^T + b; c,h fused in registers -------
__global__ __launch_bounds__(256) void node_kernel(const float* __restrict__ h_sum,
                                                   const float* __restrict__ c_agg,
                                                   const bf16* __restrict__ uioub,
                                                   const float* __restrict__ b_iou,
                                                   float* __restrict__ out) {
  __shared__ char ldsA[32768];
  __shared__ char ldsB[20480];
  const int m0 = blockIdx.x * 64;
  stage_tile(h_sum + (size_t)m0 * HDIM, ldsA);
  const int l = threadIdx.x & 63, w = threadIdx.x >> 6;
  const int c16 = l & 15, rg = l >> 4;
  f32x4 uacc[4][4], acc[4][4];
#pragma unroll
  for (int ai = 0; ai < 4; ++ai)
#pragma unroll
    for (int bj = 0; bj < 4; ++bj) uacc[ai][bj] = (f32x4){0.f, 0.f, 0.f, 0.f};
  // pass u (U_iou rows 512..767)
  for (int kc = 0; kc < 8; ++kc) {
    __syncthreads();
    stage_chunk(uioub + 2 * 65536, kc, ldsB);
    __syncthreads();
    mfma_kc(ldsA, ldsB, kc, uacc);
  }
#pragma unroll
  for (int ai = 0; ai < 4; ++ai)
#pragma unroll
    for (int bj = 0; bj < 4; ++bj) {
      const float bu = b_iou[512 + w * 64 + bj * 16 + c16];
#pragma unroll
      for (int r = 0; r < 4; ++r) uacc[ai][bj][r] += bu;
    }
  // pass i (rows 0..255): c = sigm(i)*tanh(u) + c_agg; c kept in uacc
#pragma unroll
  for (int ai = 0; ai < 4; ++ai)
#pragma unroll
    for (int bj = 0; bj < 4; ++bj) acc[ai][bj] = (f32x4){0.f, 0.f, 0.f, 0.f};
  for (int kc = 0; kc < 8; ++kc) {
    __syncthreads();
    stage_chunk(uioub, kc, ldsB);
    __syncthreads();
    mfma_kc(ldsA, ldsB, kc, acc);
  }
#pragma unroll
  for (int ai = 0; ai < 4; ++ai)
#pragma unroll
    for (int bj = 0; bj < 4; ++bj) {
      const int col = w * 64 + bj * 16 + c16;
      const float bi = b_iou[col];
#pragma unroll
      for (int r = 0; r < 4; ++r) {
        const int row = m0 + ai * 16 + rg * 4 + r;
        float cc = sigm(acc[ai][bj][r] + bi) * tanh_(uacc[ai][bj][r]) +
                   c_agg[(size_t)row * HDIM + col];
        out[(size_t)N_NODES * HDIM + (size_t)row * HDIM + col] = cc;  // c output
        uacc[ai][bj][r] = cc;
      }
    }
  // pass o (rows 256..511): h = sigm(o)*tanh(c)
#pragma unroll
  for (int ai = 0; ai < 4; ++ai)
#pragma unroll
    for (int bj = 0; bj < 4; ++bj) acc[ai][bj] = (f32x4){0.f, 0.f, 0.f, 0.f};
  for (int kc = 0; kc < 8; ++kc) {
    __syncthreads();
    stage_chunk(uioub + 65536, kc, ldsB);
    __syncthreads();
    mfma_kc(ldsA, ldsB, kc, acc);
  }
#pragma unroll
  for (int ai = 0; ai < 4; ++ai)
#pragma unroll
    for (int bj = 0; bj < 4; ++bj) {
      const int col = w * 64 + bj * 16 + c16;
      const float bo = b_iou[256 + col];
#pragma unroll
      for (int r = 0; r < 4; ++r) {
        const int row = m0 + ai * 16 + rg * 4 + r;
        out[(size_t)row * HDIM + col] = sigm(acc[ai][bj][r] + bo) * tanh_(uacc[ai][bj][r]);
      }
    }
}

extern "C" void kernel_launch(void* const* d_in, const int* in_sizes, int n_in,
                              void* d_out, int out_size, void* d_ws, size_t ws_size,
                              hipStream_t stream) {
  const float* child_h = (const float*)d_in[0];
  const float* child_c = (const float*)d_in[1];
  const float* x       = (const float*)d_in[2];
  const int*   parent  = (const int*)d_in[3];
  const float* U_iou_w = (const float*)d_in[4];
  const float* b_iou   = (const float*)d_in[5];
  const float* U_f_w   = (const float*)d_in[6];
  const float* W_f_w   = (const float*)d_in[7];
  const float* W_f_b   = (const float*)d_in[8];
  float* out = (float*)d_out;

  char* ws = (char*)d_ws;
  float* h_sum = (float*)ws;                         // N*H f32 (atomic)
  float* c_agg = h_sum + (size_t)N_NODES * HDIM;     // N*H f32 (atomic)
  bf16* wfxb   = (bf16*)(c_agg + (size_t)N_NODES * HDIM);  // N*H bf16
  bf16* ufb    = wfxb + (size_t)N_NODES * HDIM;
  bf16* wfb    = ufb + 65536;
  bf16* uioub  = wfb + 65536;                        // 768*256

  // zero the contiguous atomic accumulators (h_sum, c_agg)
  hipMemsetAsync(h_sum, 0, (size_t)2 * N_NODES * HDIM * sizeof(float), stream);
  cvt_weights<<<256, 256, 0, stream>>>(U_f_w, W_f_w, U_iou_w, ufb, wfb, uioub);
  wfx_kernel<<<N_NODES / 64, 256, 0, stream>>>(x, wfb, W_f_b, wfxb);
  edge_kernel<<<E_EDGES / 64, 256, 0, stream>>>(child_h, child_c, parent, ufb, wfxb,
                                                h_sum, c_agg);
  node_kernel<<<N_NODES / 64, 256, 0, stream>>>(h_sum, c_agg, uioub, b_iou, out);
}